// Round 3
// baseline (232.294 us; speedup 1.0000x reference)
//
#include <hip/hip_runtime.h>
#include <math.h>

// GaussianSpot: out[1,B,F,D,D] = bg[b,f] + sum_k h/(2*pi*w^2) * exp(-((i-sx)^2+(j-sy)^2)/(2w^2))
// Separable per (k,b,f): ex[i] (coef folded) and ey[j]; pixel = bg + sum_k ex[i]*ey[j].
// v2: k-interleaved float2 LDS rows -> 16 ds_read_b32 per float4 becomes 2 b64 + 2 b128.
//     (LDS-unit occupancy was ~30us/CU, on par with the 33us write floor.)
// v3: fix nontemporal store — needs a native (ext_vector_type) float4, not HIP_vector_type.

#define DD 14
#define BB 512
#define FFRAMES 512
#define NF_TAB 1024
#define PAIRS_PER_BLOCK 64
#define BLOCK 256
#define LROW 18   // padded float2 row length: 16B-aligned rows, banks spread by (4p mod 32)

typedef float nat_f4 __attribute__((ext_vector_type(4)));

__global__ __launch_bounds__(BLOCK) void gauss_spot_kernel(
    const float* __restrict__ height, const float* __restrict__ width,
    const float* __restrict__ xoff, const float* __restrict__ yoff,
    const float* __restrict__ background, const float* __restrict__ target_locs,
    const int* __restrict__ n_idx, const int* __restrict__ f_tab,
    float* __restrict__ out)
{
    // LX[p][i] = (ex_k0[i], ex_k1[i])  (coef folded into x-rows)
    // LY[p][j] = (ey_k0[j], ey_k1[j])
    __shared__ __align__(16) float2 LX[PAIRS_PER_BLOCK][LROW];
    __shared__ __align__(16) float2 LY[PAIRS_PER_BLOCK][LROW];
    __shared__ float bg_s[PAIRS_PER_BLOCK];

    const int tid = threadIdx.x;
    const int pl = tid >> 2;              // 0..63
    const int sel = tid & 3;              // k*2 + isY
    const int k = sel >> 1;
    const int isY = sel & 1;
    const int pair = blockIdx.x * PAIRS_PER_BLOCK + pl;   // b*F + fi
    const int b = pair >> 9;              // F = 512
    const int fi = pair & (FFRAMES - 1);

    // ---- phase 1: 1 task per thread, 14 exps each ----
    const int n = n_idx[b];               // n_idx is [B,1]
    const int ff = f_tab[fi];
    const float loc = target_locs[(n * NF_TAB + ff) * 2 + isY]; // ch0 -> i (sx), ch1 -> j (sy)
    const int idx = k * (BB * FFRAMES) + pair;
    const float w = width[idx];
    const float off = isY ? yoff[idx] : xoff[idx];
    const float s = loc + off;
    const float inv2w2 = 1.0f / (2.0f * w * w);
    // coef = h / (2*pi*w^2) = h * inv2w2 * (1/pi); fold into x-rows only
    const float coef = isY ? 1.0f : height[idx] * inv2w2 * 0.31830988618379067f;
    const float a = inv2w2 * 1.4426950408889634f;  // log2(e)/(2w^2)

    float* dst = isY ? (float*)(&LY[pl][0]) : (float*)(&LX[pl][0]);
    #pragma unroll
    for (int i = 0; i < DD; ++i) {
        float d = (float)i - s;
        dst[2 * i + k] = coef * exp2f(-d * d * a);
    }
    if (sel == 0) bg_s[pl] = background[pair];
    __syncthreads();

    // ---- phase 2: coalesced float4 stores over block's contiguous 64*196-float region ----
    // Each float4 = 4 consecutive pixels of one AOI. pix0 = 4*(v mod 49) is a multiple of 4,
    // so j0 = pix0 mod 14 is always EVEN -> 16B-aligned float4 loads from LY.
    // Row wrap inside a float4 happens only when j0 == 12 (elements 2,3 move to row i0+1, j=0,1).
    nat_f4* outv = (nat_f4*)(out + (size_t)blockIdx.x * (PAIRS_PER_BLOCK * DD * DD));
    const int NV = PAIRS_PER_BLOCK * DD * DD / 4;   // 3136
    int p = tid / 49;                     // computed once; loop maintains incrementally
    int rem = tid - p * 49;               // v mod 49; 256 = 5*49 + 11
    for (int v = tid; v < NV; v += BLOCK) {
        const int pix0 = rem * 4;                       // 0..192
        const int i0 = (pix0 * 2341) >> 15;             // == pix0 / 14 for pix0 in [0,192]
        const int j0 = pix0 - i0 * DD;                  // even, 0..12
        const bool wrap = (j0 == 12);
        const int jb = wrap ? 0 : (j0 + 2);             // start j for elements 2,3

        const float2 xa  = LX[p][i0];                               // ds_read_b64
        const float2 x23 = LX[p][i0 + (wrap ? 1 : 0)];              // ds_read_b64 (row for e2,e3)
        const float4 ya  = *(const float4*)(&LY[p][j0]);            // ds_read_b128: j0, j0+1
        const float4 yb  = *(const float4*)(&LY[p][jb]);            // ds_read_b128: jb, jb+1
        const float bg = bg_s[p];

        nat_f4 r;
        r.x = fmaf(xa.y,  ya.y, fmaf(xa.x,  ya.x, bg));
        r.y = fmaf(xa.y,  ya.w, fmaf(xa.x,  ya.z, bg));
        r.z = fmaf(x23.y, yb.y, fmaf(x23.x, yb.x, bg));
        r.w = fmaf(x23.y, yb.w, fmaf(x23.x, yb.z, bg));
        __builtin_nontemporal_store(r, &outv[v]);

        rem += 11; p += 5;
        if (rem >= 49) { rem -= 49; p += 1; }
    }
}

extern "C" void kernel_launch(void* const* d_in, const int* in_sizes, int n_in,
                              void* d_out, int out_size, void* d_ws, size_t ws_size,
                              hipStream_t stream) {
    const float* height      = (const float*)d_in[0];
    const float* width       = (const float*)d_in[1];
    const float* x           = (const float*)d_in[2];
    const float* y           = (const float*)d_in[3];
    const float* background  = (const float*)d_in[4];
    const float* target_locs = (const float*)d_in[5];
    const int*   n_idx       = (const int*)d_in[6];
    const int*   f           = (const int*)d_in[7];
    float* out = (float*)d_out;

    const int total_pairs = BB * FFRAMES;              // 262144
    const int grid = total_pairs / PAIRS_PER_BLOCK;    // 4096
    gauss_spot_kernel<<<grid, BLOCK, 0, stream>>>(
        height, width, x, y, background, target_locs, n_idx, f, out);
}

// Round 4
// 222.058 us; speedup vs baseline: 1.0461x; 1.0461x over previous
//
#include <hip/hip_runtime.h>
#include <math.h>

// GaussianSpot: out[1,B,F,D,D] = bg[b,f] + sum_k h/(2*pi*w^2) * exp(-((i-sx)^2+(j-sy)^2)/(2w^2))
// Separable per (k,b,f): ex[i] (coef folded) and ey[j]; pixel = bg + sum_k ex[i]*ey[j].
// v2: k-interleaved float2 LDS rows -> 16 ds_read_b32 per float4 becomes 2 b64 + 2 b128.
// v4: A/B — revert nontemporal store to plain store (v3 residual regressed +5.8us vs fill drift;
//     nt bypasses L2 write-combine and is the only kernel-side change that round).

#define DD 14
#define BB 512
#define FFRAMES 512
#define NF_TAB 1024
#define PAIRS_PER_BLOCK 64
#define BLOCK 256
#define LROW 18   // padded float2 row length: 16B-aligned rows, banks spread by (4p mod 32)

__global__ __launch_bounds__(BLOCK) void gauss_spot_kernel(
    const float* __restrict__ height, const float* __restrict__ width,
    const float* __restrict__ xoff, const float* __restrict__ yoff,
    const float* __restrict__ background, const float* __restrict__ target_locs,
    const int* __restrict__ n_idx, const int* __restrict__ f_tab,
    float* __restrict__ out)
{
    // LX[p][i] = (ex_k0[i], ex_k1[i])  (coef folded into x-rows)
    // LY[p][j] = (ey_k0[j], ey_k1[j])
    __shared__ __align__(16) float2 LX[PAIRS_PER_BLOCK][LROW];
    __shared__ __align__(16) float2 LY[PAIRS_PER_BLOCK][LROW];
    __shared__ float bg_s[PAIRS_PER_BLOCK];

    const int tid = threadIdx.x;
    const int pl = tid >> 2;              // 0..63
    const int sel = tid & 3;              // k*2 + isY
    const int k = sel >> 1;
    const int isY = sel & 1;
    const int pair = blockIdx.x * PAIRS_PER_BLOCK + pl;   // b*F + fi
    const int b = pair >> 9;              // F = 512
    const int fi = pair & (FFRAMES - 1);

    // ---- phase 1: 1 task per thread, 14 exps each ----
    const int n = n_idx[b];               // n_idx is [B,1]
    const int ff = f_tab[fi];
    const float loc = target_locs[(n * NF_TAB + ff) * 2 + isY]; // ch0 -> i (sx), ch1 -> j (sy)
    const int idx = k * (BB * FFRAMES) + pair;
    const float w = width[idx];
    const float off = isY ? yoff[idx] : xoff[idx];
    const float s = loc + off;
    const float inv2w2 = 1.0f / (2.0f * w * w);
    // coef = h / (2*pi*w^2) = h * inv2w2 * (1/pi); fold into x-rows only
    const float coef = isY ? 1.0f : height[idx] * inv2w2 * 0.31830988618379067f;
    const float a = inv2w2 * 1.4426950408889634f;  // log2(e)/(2w^2)

    float* dst = isY ? (float*)(&LY[pl][0]) : (float*)(&LX[pl][0]);
    #pragma unroll
    for (int i = 0; i < DD; ++i) {
        float d = (float)i - s;
        dst[2 * i + k] = coef * exp2f(-d * d * a);
    }
    if (sel == 0) bg_s[pl] = background[pair];
    __syncthreads();

    // ---- phase 2: coalesced float4 stores over block's contiguous 64*196-float region ----
    // Each float4 = 4 consecutive pixels of one AOI. pix0 = 4*(v mod 49) is a multiple of 4,
    // so j0 = pix0 mod 14 is always EVEN -> 16B-aligned float4 loads from LY.
    // Row wrap inside a float4 happens only when j0 == 12 (elements 2,3 move to row i0+1, j=0,1).
    float4* outv = (float4*)(out + (size_t)blockIdx.x * (PAIRS_PER_BLOCK * DD * DD));
    const int NV = PAIRS_PER_BLOCK * DD * DD / 4;   // 3136
    int p = tid / 49;                     // computed once; loop maintains incrementally
    int rem = tid - p * 49;               // v mod 49; 256 = 5*49 + 11
    for (int v = tid; v < NV; v += BLOCK) {
        const int pix0 = rem * 4;                       // 0..192
        const int i0 = (pix0 * 2341) >> 15;             // == pix0 / 14 for pix0 in [0,192]
        const int j0 = pix0 - i0 * DD;                  // even, 0..12
        const bool wrap = (j0 == 12);
        const int jb = wrap ? 0 : (j0 + 2);             // start j for elements 2,3

        const float2 xa  = LX[p][i0];                               // ds_read_b64
        const float2 x23 = LX[p][i0 + (wrap ? 1 : 0)];              // ds_read_b64 (row for e2,e3)
        const float4 ya  = *(const float4*)(&LY[p][j0]);            // ds_read_b128: j0, j0+1
        const float4 yb  = *(const float4*)(&LY[p][jb]);            // ds_read_b128: jb, jb+1
        const float bg = bg_s[p];

        float4 r;
        r.x = fmaf(xa.y,  ya.y, fmaf(xa.x,  ya.x, bg));
        r.y = fmaf(xa.y,  ya.w, fmaf(xa.x,  ya.z, bg));
        r.z = fmaf(x23.y, yb.y, fmaf(x23.x, yb.x, bg));
        r.w = fmaf(x23.y, yb.w, fmaf(x23.x, yb.z, bg));
        outv[v] = r;

        rem += 11; p += 5;
        if (rem >= 49) { rem -= 49; p += 1; }
    }
}

extern "C" void kernel_launch(void* const* d_in, const int* in_sizes, int n_in,
                              void* d_out, int out_size, void* d_ws, size_t ws_size,
                              hipStream_t stream) {
    const float* height      = (const float*)d_in[0];
    const float* width       = (const float*)d_in[1];
    const float* x           = (const float*)d_in[2];
    const float* y           = (const float*)d_in[3];
    const float* background  = (const float*)d_in[4];
    const float* target_locs = (const float*)d_in[5];
    const int*   n_idx       = (const int*)d_in[6];
    const int*   f           = (const int*)d_in[7];
    float* out = (float*)d_out;

    const int total_pairs = BB * FFRAMES;              // 262144
    const int grid = total_pairs / PAIRS_PER_BLOCK;    // 4096
    gauss_spot_kernel<<<grid, BLOCK, 0, stream>>>(
        height, width, x, y, background, target_locs, n_idx, f, out);
}